// Round 3
// baseline (97.757 us; speedup 1.0000x reference)
//
#include <hip/hip_runtime.h>
#include <math.h>

#define M_TOT 87296
#define NB    1364          // 64 locations x 4 subs = 256 threads per block
#define INF_F 100000000.0f

// d_ws layout (floats):
//   [0]           : int completion counter (memset to 0 each launch)
//   [1..3]        : pad
//   [4      ..4+NB)   : per-block reg_sum
//   [4+NB   ..4+2NB)  : per-block reg_cnt
//   [4+2NB  ..4+3NB)  : per-block neg_sum

__global__ __launch_bounds__(256, 4) void fused_kernel(
    const float* __restrict__ boxes,     // [4,64,4]
    const float* __restrict__ agn,       // [M_TOT]
    const float* __restrict__ reg_pred,  // [M_TOT,4]
    float* __restrict__ ws,
    float* __restrict__ out)
{
    __shared__ float4 sA[64];   // x1,y1,x2,y2
    __shared__ float4 sB[64];   // qx,qy,cx,cy
    __shared__ float  sC[64];   // 1/radius2
    __shared__ float  sRed[12]; // 4 waves x 3 partials
    __shared__ int    sLast;

    const int t     = threadIdx.x;
    const int blk   = blockIdx.x;
    const int mbase = blk * 64;

    // every block is single-level AND single-image (all chunk sizes are multiples of 64)
    int lev;
    if      (mbase < 65536) lev = 0;
    else if (mbase < 81920) lev = 1;
    else if (mbase < 86016) lev = 2;
    else if (mbase < 87040) lev = 3;
    else                    lev = 4;

    const int   LB_[5]   = {0, 65536, 81920, 86016, 87040};
    const int   locSh[5] = {14, 12, 10, 8, 6};
    const int   wSh[5]   = {7, 6, 5, 4, 3};
    const float SV[5]    = {8.f, 16.f, 32.f, 64.f, 128.f};
    const float LOv[5]   = {0.f, 64.f, 128.f, 256.f, 512.f};
    const float HIv[5]   = {80.f, 160.f, 320.f, 640.f, 10000000.f};

    const float s     = SV[lev];
    const float inv_s = 1.0f / s;      // s is a power of 2: exact reciprocal
    const float half  = 0.5f * s;
    const int   bimg  = (mbase - LB_[lev]) >> locSh[lev];

    if (t < 64) {
        const float4 bx = ((const float4*)boxes)[bimg * 64 + t];
        const float cx = (bx.x + bx.z) * 0.5f;
        const float cy = (bx.y + bx.w) * 0.5f;
        // *inv_s is bit-identical to /s (power of 2); truncf == int32 cast (centers >= 0)
        const float qx = truncf(cx * inv_s) * s + half;
        const float qy = truncf(cy * inv_s) * s + half;
        const float area = (bx.z - bx.x) * (bx.w - bx.y);
        const double DELTA = (1.0 - 0.8) / (1.0 + 0.8);
        const float RADC = (float)(DELTA * DELTA * 2.0);
        const float r2 = fmaxf(RADC * area, 16.0f);
        sA[t] = bx;
        sB[t] = make_float4(qx, qy, cx, cy);
        sC[t] = 1.0f / r2;
    }
    __syncthreads();

    const int   mloc = mbase + (t >> 2);
    const int   sub  = t & 3;
    const int   p    = (mloc - LB_[lev]) & ((1 << locSh[lev]) - 1);
    const float gx   = (float)(p & ((1 << wSh[lev]) - 1)) * s + half;
    const float gy   = (float)(p >> wSh[lev]) * s + half;
    const float lo   = LOv[lev], hi = HIv[lev];

    float minW = INF_F;
    unsigned long long bestKey = ~0ULL;

    #pragma unroll
    for (int k = 0; k < 16; ++k) {
        const int n = k * 4 + sub;          // quad lanes read 4 consecutive slots (broadcast-friendly)
        const float4 A  = sA[n];
        const float4 Bv = sB[n];
        const float  ir2 = sC[n];

        const float l  = gx - A.x;
        const float tt = gy - A.y;
        const float rr = A.z - gx;
        const float bb = A.w - gy;
        const bool is_in = fminf(fminf(l, tt), fminf(rr, bb)) > 0.0f;

        const float dx = gx - Bv.x, dy = gy - Bv.y;
        const bool is_peak = (dx * dx + dy * dy) == 0.0f;
        const bool c3 = (fabsf(dx) <= s) && (fabsf(dy) <= s) && is_in;

        const float wsum = l + rr, hsum = tt + bb;      // same FP order as reference
        const float crit = sqrtf(wsum * wsum + hsum * hsum) * 0.5f;
        const bool msk = c3 && (crit >= lo) && (crit <= hi);

        const float ddx = gx - Bv.z, ddy = gy - Bv.w;
        const float dist2 = is_peak ? 0.0f : (ddx * ddx + ddy * ddy);
        const float w2 = dist2 * ir2;
        minW = fminf(minW, w2);

        const float d = msk ? w2 : INF_F;
        // nonneg float bits are order-preserving; key min == (min d, then min n)
        const unsigned long long key =
            ((unsigned long long)__float_as_uint(d) << 6) | (unsigned)n;
        bestKey = key < bestKey ? key : bestKey;
    }

    // combine the 4 sub-lanes handling the same location
    {
        unsigned long long o = __shfl_xor(bestKey, 1);
        bestKey = o < bestKey ? o : bestKey;
        o = __shfl_xor(bestKey, 2);
        bestKey = o < bestKey ? o : bestKey;
        float w = __shfl_xor(minW, 1); minW = fminf(minW, w);
        w = __shfl_xor(minW, 2);       minW = fminf(minW, w);
    }

    float reg_term = 0.0f, reg_val = 0.0f, neg_term = 0.0f;
    if (sub == 0) {
        float hmv = expf(-minW);
        if (hmv < 1e-4f) hmv = 0.0f;
        const float u = 1.0f - hmv;
        const float u2 = u * u;
        const float neg_w = u2 * u2;                   // (1-hm)^4 via multiplies

        const float z = agn[mloc];
        float pr = 1.0f / (1.0f + expf(-z));
        pr = fminf(fmaxf(pr, 1e-4f), 1.0f - 1e-4f);
        if (pr < 0.85f) neg_term = logf(1.0f - pr) * (pr * pr) * neg_w;

        const unsigned dbits = (unsigned)(bestKey >> 6);
        if (dbits < __float_as_uint(INF_F)) {
            reg_val = 1.0f;
            const int n = (int)(bestKey & 63);
            const float4 A = sA[n];
            const float tl  = (gx - A.x) * inv_s;      // bit-exact vs /s
            const float tt2 = (gy - A.y) * inv_s;
            const float tr  = (A.z - gx) * inv_s;
            const float tb  = (A.w - gy) * inv_s;
            const float4 pv = ((const float4*)reg_pred)[mloc];
            const float pl = pv.x, pt = pv.y, prr = pv.z, pb = pv.w;
            const float target_area = (tl + tr) * (tt2 + tb);
            const float pred_area   = (pl + prr) * (pt + pb);
            const float w_i = fminf(pl, tl) + fminf(prr, tr);
            const float g_w = fmaxf(pl, tl) + fmaxf(prr, tr);
            const float h_i = fminf(pb, tb) + fminf(pt, tt2);
            const float g_h = fmaxf(pb, tb) + fmaxf(pt, tt2);
            const float ac    = g_w * g_h + 1e-7f;
            const float inter = w_i * h_i;
            const float uni   = target_area + pred_area - inter;
            const float ious  = (inter + 1.0f) / (uni + 1.0f);
            const float gious = ious - (ac - uni) / ac;
            reg_term = 1.0f - gious;
        }
    }

    // wave(64) reduction, then 4-wave LDS reduce -> per-block partial slots
    for (int off = 32; off; off >>= 1) {
        reg_term += __shfl_down(reg_term, off);
        reg_val  += __shfl_down(reg_val,  off);
        neg_term += __shfl_down(neg_term, off);
    }
    if ((t & 63) == 0) {
        const int w = t >> 6;
        sRed[w * 3 + 0] = reg_term;
        sRed[w * 3 + 1] = reg_val;
        sRed[w * 3 + 2] = neg_term;
    }
    __syncthreads();
    if (t == 0) {
        ws[4 + blk]          = sRed[0] + sRed[3] + sRed[6] + sRed[9];
        ws[4 + NB + blk]     = sRed[1] + sRed[4] + sRed[7] + sRed[10];
        ws[4 + 2 * NB + blk] = sRed[2] + sRed[5] + sRed[8] + sRed[11];
        __threadfence();                                   // release partials (device scope)
        const int old = atomicAdd((int*)ws, 1);
        sLast = (old == NB - 1);
    }
    __syncthreads();
    if (!sLast) return;

    // ---- last block: finalize (partials + pos terms + outputs) ----
    __threadfence();                                       // acquire

    float racc = 0.0f, cacc = 0.0f, nacc = 0.0f;
    for (int j = t; j < NB; j += 256) {
        racc += ws[4 + j];
        cacc += ws[4 + NB + j];
        nacc += ws[4 + 2 * NB + j];
    }

    const int   BAS[5] = {0, 65536, 81920, 86016, 87040};
    const int   LOC[5] = {16384, 4096, 1024, 256, 64};
    const int   WW[5]  = {128, 64, 32, 16, 8};
    const float ST[5]  = {8.f, 16.f, 32.f, 64.f, 128.f};

    float psum = 0.0f, pcnt = 0.0f;
    for (int j = t; j < 1280; j += 256) {   // [B,N,L] flattened, L fastest
        const int plev = j % 5;
        const int bn   = j / 5;
        const int b    = bn >> 6;
        const float4 bx = ((const float4*)boxes)[bn];
        const float cx = (bx.x + bx.z) * 0.5f;
        const float cy = (bx.y + bx.w) * 0.5f;
        const int cix = (int)(cx / ST[plev]);
        const int ciy = (int)(cy / ST[plev]);
        int pos = BAS[plev] + b * LOC[plev] + ciy * WW[plev] + cix;
        pos = min(max(pos, 0), M_TOT - 1);
        const float dx = bx.z - bx.x, dy = bx.w - bx.y;
        const float crit = sqrtf(dx * dx + dy * dy) * 0.5f;
        const bool msk = (crit >= LOv[plev]) && (crit <= HIv[plev]);
        const float z = agn[pos];
        float pp = 1.0f / (1.0f + expf(-z));
        pp = fminf(fmaxf(pp, 1e-4f), 1.0f - 1e-4f);
        if (msk) {
            const float om = 1.0f - pp;
            psum += logf(pp) * (om * om);
            pcnt += 1.0f;
        }
    }

    for (int off = 32; off; off >>= 1) {
        racc += __shfl_down(racc, off);
        cacc += __shfl_down(cacc, off);
        nacc += __shfl_down(nacc, off);
        psum += __shfl_down(psum, off);
        pcnt += __shfl_down(pcnt, off);
    }
    __shared__ float sr[4][5];
    if ((t & 63) == 0) {
        const int w = t >> 6;
        sr[w][0] = racc; sr[w][1] = cacc; sr[w][2] = nacc;
        sr[w][3] = psum; sr[w][4] = pcnt;
    }
    __syncthreads();
    if (t == 0) {
        const float RS = sr[0][0] + sr[1][0] + sr[2][0] + sr[3][0];
        const float RC = sr[0][1] + sr[1][1] + sr[2][1] + sr[3][1];
        const float NS = sr[0][2] + sr[1][2] + sr[2][2] + sr[3][2];
        const float PS = sr[0][3] + sr[1][3] + sr[2][3] + sr[3][3];
        const float PC = sr[0][4] + sr[1][4] + sr[2][4] + sr[3][4];
        const float num_pos  = fmaxf(PC, 1.0f);
        const float reg_norm = fmaxf(RC, 1.0f);
        out[0] = RS / reg_norm;                     // REG_WEIGHT = 1
        out[1] = 0.5f * (0.25f * -PS) / num_pos;    // POS_W * ALPHA
        out[2] = 0.5f * (0.75f * -NS) / num_pos;    // NEG_W * (1-ALPHA)
    }
}

extern "C" void kernel_launch(void* const* d_in, const int* in_sizes, int n_in,
                              void* d_out, int out_size, void* d_ws, size_t ws_size,
                              hipStream_t stream) {
    const float* boxes    = (const float*)d_in[0];   // [4,64,4] f32
    // d_in[1] = gt_classes (unused)
    const float* agn      = (const float*)d_in[2];   // [87296] f32
    const float* reg_pred = (const float*)d_in[3];   // [87296,4] f32
    float* out = (float*)d_out;
    float* ws  = (float*)d_ws;

    hipMemsetAsync(d_ws, 0, 4, stream);              // zero the completion counter
    fused_kernel<<<NB, 256, 0, stream>>>(boxes, agn, reg_pred, ws, out);
}

// Round 4
// 77.636 us; speedup vs baseline: 1.2592x; 1.2592x over previous
//
#include <hip/hip_runtime.h>
#include <math.h>

#define M_TOT 87296
#define NBLK  341           // main blocks (256 locs each); block NBLK computes pos-terms
#define INF_F 100000000.0f

// ws layout (floats): [0..NBLK) reg_sum, [NBLK..2N) reg_cnt, [2N..3N) neg_sum,
//                     [3N] = psum, [3N+1] = pcnt

__global__ __launch_bounds__(256, 2) void main_kernel(
    const float* __restrict__ boxes,     // [4,64,4]
    const float* __restrict__ agn,       // [M_TOT]
    const float* __restrict__ reg_pred,  // [M_TOT,4]
    float* __restrict__ partial)
{
    __shared__ float4 sBox[256];   // all 4 images' boxes (4 KB)
    __shared__ float  sRed[16];

    const int t   = threadIdx.x;
    const int blk = blockIdx.x;

    if (blk == NBLK) {
        // ---- pos-terms block (independent of the assignment) ----
        const int   BAS[5] = {0, 65536, 81920, 86016, 87040};
        const int   LOC[5] = {16384, 4096, 1024, 256, 64};
        const int   WW[5]  = {128, 64, 32, 16, 8};
        const float ST[5]  = {8.f, 16.f, 32.f, 64.f, 128.f};
        const float PLO[5] = {0.f, 64.f, 128.f, 256.f, 512.f};
        const float PHI[5] = {80.f, 160.f, 320.f, 640.f, 10000000.f};
        float psum = 0.f, pcnt = 0.f;
        for (int j = t; j < 1280; j += 256) {     // [B,N,L] flattened, L fastest
            const int lev = j % 5;
            const int bn  = j / 5;
            const int b   = bn >> 6;
            const float4 bx = ((const float4*)boxes)[bn];
            const float cx = (bx.x + bx.z) * 0.5f;
            const float cy = (bx.y + bx.w) * 0.5f;
            const int cix = (int)(cx / ST[lev]);
            const int ciy = (int)(cy / ST[lev]);
            int pos = BAS[lev] + b * LOC[lev] + ciy * WW[lev] + cix;
            pos = min(max(pos, 0), M_TOT - 1);
            const float dx = bx.z - bx.x, dy = bx.w - bx.y;
            const float crit = sqrtf(dx * dx + dy * dy) * 0.5f;
            const bool msk = (crit >= PLO[lev]) && (crit <= PHI[lev]);
            const float z = agn[pos];
            float pp = 1.0f / (1.0f + expf(-z));
            pp = fminf(fmaxf(pp, 1e-4f), 1.0f - 1e-4f);
            if (msk) {
                const float om = 1.0f - pp;
                psum += logf(pp) * (om * om);
                pcnt += 1.0f;
            }
        }
        for (int off = 32; off; off >>= 1) {
            psum += __shfl_down(psum, off);
            pcnt += __shfl_down(pcnt, off);
        }
        if ((t & 63) == 0) { sRed[t >> 6] = psum; sRed[4 + (t >> 6)] = pcnt; }
        __syncthreads();
        if (t == 0) {
            partial[3 * NBLK]     = sRed[0] + sRed[1] + sRed[2] + sRed[3];
            partial[3 * NBLK + 1] = sRed[4] + sRed[5] + sRed[6] + sRed[7];
        }
        return;
    }

    // ---- main: 256 consecutive locations; 8 subs x 8 boxes x 8 locs per thread ----
    const int mbase = blk << 8;
    int lev;
    if      (mbase < 65536) lev = 0;
    else if (mbase < 81920) lev = 1;
    else if (mbase < 86016) lev = 2;
    else if (mbase < 87040) lev = 3;
    else                    lev = 4;

    const int   LB_[5]   = {0, 65536, 81920, 86016, 87040};
    const int   locSh[5] = {14, 12, 10, 8, 6};
    const int   wSh[5]   = {7, 6, 5, 4, 3};
    const float SV[5]    = {8.f, 16.f, 32.f, 64.f, 128.f};
    const float LOv[5]   = {0.f, 64.f, 128.f, 256.f, 512.f};
    const float HIv[5]   = {80.f, 160.f, 320.f, 640.f, 10000000.f};

    const int   LB    = LB_[lev];
    const int   lsh   = locSh[lev];
    const int   wsh   = wSh[lev];
    const float s     = SV[lev];
    const float inv_s = 1.0f / s;      // s is a power of 2: exact reciprocal
    const float half  = 0.5f * s;
    const float lo    = LOv[lev], hi = HIv[lev];

    sBox[t] = ((const float4*)boxes)[t];     // coalesced stage of all 256 boxes
    __syncthreads();

    const int g       = t >> 3;              // 32 groups x 8 locations
    const int su      = t & 7;               // sub-lane: boxes su+8k
    const int locBase = mbase + g * 8;       // group's 8 locs lie in ONE image
    const int imgBase = ((locBase - LB) >> lsh) << 6;

    const double DELTA = (1.0 - 0.8) / (1.0 + 0.8);
    const float  RADC  = (float)(DELTA * DELTA * 2.0);

    // register-resident box state (independent LDS loads -> one wait, then pure VALU)
    float bx1[8], by1[8], bx2[8], by2[8], bcx[8], bcy[8], bqx[8], bqy[8], bir[8];
    #pragma unroll
    for (int k = 0; k < 8; ++k) {
        const float4 A = sBox[imgBase + su + 8 * k];
        bx1[k] = A.x; by1[k] = A.y; bx2[k] = A.z; by2[k] = A.w;
        bcx[k] = (A.x + A.z) * 0.5f;
        bcy[k] = (A.y + A.w) * 0.5f;
        // *inv_s bit-identical to /s (pow2); truncf == int32 cast (centers >= 0)
        bqx[k] = truncf(bcx[k] * inv_s) * s + half;
        bqy[k] = truncf(bcy[k] * inv_s) * s + half;
        const float area = (A.z - A.x) * (A.w - A.y);
        bir[k] = 1.0f / fmaxf(RADC * area, 16.0f);
    }

    float minW[8], bestD[8];
    int   bestN[8];
    #pragma unroll
    for (int j = 0; j < 8; ++j) { minW[j] = INF_F; bestD[j] = INF_F; bestN[j] = 0; }

    #pragma unroll
    for (int j = 0; j < 8; ++j) {
        const int   p  = (locBase + j - LB) & ((1 << lsh) - 1);
        const float gx = (float)(p & ((1 << wsh) - 1)) * s + half;
        const float gy = (float)(p >> wsh) * s + half;
        #pragma unroll
        for (int k = 0; k < 8; ++k) {
            const float l  = gx - bx1[k];
            const float tt = gy - by1[k];
            const float rr = bx2[k] - gx;
            const float bb = by2[k] - gy;
            const bool is_in = fminf(fminf(l, tt), fminf(rr, bb)) > 0.0f;
            const float dx = gx - bqx[k], dy = gy - bqy[k];
            const bool is_peak = (dx * dx + dy * dy) == 0.0f;
            const bool c3 = (fabsf(dx) <= s) && (fabsf(dy) <= s) && is_in;
            const float wsum = l + rr, hsum = tt + bb;   // reference FP order
            const float crit = sqrtf(wsum * wsum + hsum * hsum) * 0.5f;
            const bool msk = c3 && (crit >= lo) && (crit <= hi);
            const float ddx = gx - bcx[k], ddy = gy - bcy[k];
            const float dist2 = is_peak ? 0.0f : (ddx * ddx + ddy * ddy);
            const float w2 = dist2 * bir[k];
            minW[j] = fminf(minW[j], w2);
            const float d = msk ? w2 : INF_F;            // w2 < 1e8 always
            if (d < bestD[j]) { bestD[j] = d; bestN[j] = su + 8 * k; }  // ascending n
        }
    }

    // cross-sub reduce per slot j; lane su keeps slot j==su -> lane t owns loc mbase+t
    unsigned long long myKey = 0; float myMinW = 0.f;
    #pragma unroll
    for (int j = 0; j < 8; ++j) {
        // nonneg float bits order-preserving; min key == (min d, then min n) == first-min
        unsigned long long kj =
            ((unsigned long long)__float_as_uint(bestD[j]) << 6) | (unsigned)bestN[j];
        float wj = minW[j];
        #pragma unroll
        for (int m = 1; m < 8; m <<= 1) {
            const unsigned long long o = __shfl_xor(kj, m);
            kj = o < kj ? o : kj;
            wj = fminf(wj, __shfl_xor(wj, m));
        }
        if (su == j) { myKey = kj; myMinW = wj; }
    }

    // full-lane epilogue, coalesced agn/reg_pred
    const int myloc = mbase + t;
    float hmv = expf(-myMinW);
    if (hmv < 1e-4f) hmv = 0.0f;
    const float u = 1.0f - hmv;
    const float neg_w = (u * u) * (u * u);
    const float z = agn[myloc];
    float pr = 1.0f / (1.0f + expf(-z));
    pr = fminf(fmaxf(pr, 1e-4f), 1.0f - 1e-4f);
    float neg_term = 0.f, reg_term = 0.f, reg_val = 0.f;
    if (pr < 0.85f) neg_term = logf(1.0f - pr) * (pr * pr) * neg_w;

    if ((unsigned)(myKey >> 6) < __float_as_uint(INF_F)) {
        reg_val = 1.0f;
        const int n = (int)(myKey & 63);
        const int myImgBase = ((myloc - LB) >> lsh) << 6;
        const float4 A = sBox[myImgBase + n];
        const int   p  = (myloc - LB) & ((1 << lsh) - 1);
        const float gx = (float)(p & ((1 << wsh) - 1)) * s + half;
        const float gy = (float)(p >> wsh) * s + half;
        const float tl  = (gx - A.x) * inv_s;
        const float tt2 = (gy - A.y) * inv_s;
        const float tr  = (A.z - gx) * inv_s;
        const float tb  = (A.w - gy) * inv_s;
        const float4 pv = ((const float4*)reg_pred)[myloc];
        const float pl = pv.x, pt = pv.y, prr = pv.z, pb = pv.w;
        const float target_area = (tl + tr) * (tt2 + tb);
        const float pred_area   = (pl + prr) * (pt + pb);
        const float w_i = fminf(pl, tl) + fminf(prr, tr);
        const float g_w = fmaxf(pl, tl) + fmaxf(prr, tr);
        const float h_i = fminf(pb, tb) + fminf(pt, tt2);
        const float g_h = fmaxf(pb, tb) + fmaxf(pt, tt2);
        const float ac    = g_w * g_h + 1e-7f;
        const float inter = w_i * h_i;
        const float uni   = target_area + pred_area - inter;
        const float ious  = (inter + 1.0f) / (uni + 1.0f);
        const float gious = ious - (ac - uni) / ac;
        reg_term = 1.0f - gious;
    }

    float r0 = reg_term, r1 = reg_val, r2 = neg_term;
    for (int off = 32; off; off >>= 1) {
        r0 += __shfl_down(r0, off);
        r1 += __shfl_down(r1, off);
        r2 += __shfl_down(r2, off);
    }
    if ((t & 63) == 0) {
        const int w = t >> 6;
        sRed[w * 3 + 0] = r0; sRed[w * 3 + 1] = r1; sRed[w * 3 + 2] = r2;
    }
    __syncthreads();
    if (t == 0) {
        partial[blk]            = sRed[0] + sRed[3] + sRed[6] + sRed[9];
        partial[NBLK + blk]     = sRed[1] + sRed[4] + sRed[7] + sRed[10];
        partial[2 * NBLK + blk] = sRed[2] + sRed[5] + sRed[8] + sRed[11];
    }
}

__global__ __launch_bounds__(256) void finalize(
    const float* __restrict__ partial,
    float* __restrict__ out)
{
    const int t = threadIdx.x;
    float racc = 0.f, cacc = 0.f, nacc = 0.f;
    for (int j = t; j < NBLK; j += 256) {
        racc += partial[j];
        cacc += partial[NBLK + j];
        nacc += partial[2 * NBLK + j];
    }
    for (int off = 32; off; off >>= 1) {
        racc += __shfl_down(racc, off);
        cacc += __shfl_down(cacc, off);
        nacc += __shfl_down(nacc, off);
    }
    __shared__ float sr[4][3];
    if ((t & 63) == 0) {
        const int w = t >> 6;
        sr[w][0] = racc; sr[w][1] = cacc; sr[w][2] = nacc;
    }
    __syncthreads();
    if (t == 0) {
        const float RS = sr[0][0] + sr[1][0] + sr[2][0] + sr[3][0];
        const float RC = sr[0][1] + sr[1][1] + sr[2][1] + sr[3][1];
        const float NS = sr[0][2] + sr[1][2] + sr[2][2] + sr[3][2];
        const float PS = partial[3 * NBLK];
        const float PC = partial[3 * NBLK + 1];
        const float num_pos  = fmaxf(PC, 1.0f);
        const float reg_norm = fmaxf(RC, 1.0f);
        out[0] = RS / reg_norm;                     // REG_WEIGHT = 1
        out[1] = 0.5f * (0.25f * -PS) / num_pos;    // POS_W * ALPHA
        out[2] = 0.5f * (0.75f * -NS) / num_pos;    // NEG_W * (1-ALPHA)
    }
}

extern "C" void kernel_launch(void* const* d_in, const int* in_sizes, int n_in,
                              void* d_out, int out_size, void* d_ws, size_t ws_size,
                              hipStream_t stream) {
    const float* boxes    = (const float*)d_in[0];   // [4,64,4] f32
    // d_in[1] = gt_classes (unused)
    const float* agn      = (const float*)d_in[2];   // [87296] f32
    const float* reg_pred = (const float*)d_in[3];   // [87296,4] f32
    float* out = (float*)d_out;
    float* ws  = (float*)d_ws;

    main_kernel<<<NBLK + 1, 256, 0, stream>>>(boxes, agn, reg_pred, ws);
    finalize<<<1, 256, 0, stream>>>(ws, out);
}